// Round 16
// baseline (197.010 us; speedup 1.0000x reference)
//
#include <hip/hip_runtime.h>

#define F_IN 128
#define HID  64
#define NCLS 16

#define BSHIFT 8            // 256 nodes per bucket
#define BNODES 256
#define NB_MAX 512          // max buckets (N<=128k)
#define CHUNK  8192         // edges per partition block
#define CAP    8192         // fixed part[] slot per bucket (mean 4352, 50+ sigma margin)
#define PADB   772          // csr per-bucket padding slack: 256 rows * 3 + align
#define CAPP   (CAP + PADB) // fixed csr slot per bucket (8964, multiple of 4)

typedef __attribute__((ext_vector_type(2))) float f32x2;
typedef __attribute__((ext_vector_type(8))) short bf16x8;
typedef __attribute__((ext_vector_type(4))) float f32x4;

// round-to-nearest-even fp32 -> bf16
__device__ __forceinline__ unsigned short f2bf(float f) {
    unsigned int u = __float_as_uint(f);
    u += 0x7FFFu + ((u >> 16) & 1u);
    return (unsigned short)(u >> 16);
}
// one dword = 2 packed bf16 -> f32x2 (2 VALU unpack + packed add)
// NOTE: do NOT replace with __builtin_amdgcn_fdot2_f32_bf16 — it compiles on
// gfx950 but produces wrong numerics (round-9 failure, absmax 0.57).
__device__ __forceinline__ f32x2 bfpair(unsigned int u) {
    f32x2 r;
    r.x = __uint_as_float(u << 16);
    r.y = __uint_as_float(u & 0xFFFF0000u);
    return r;
}

// ---------- init (1 block): zero cursors + w1t conversion + h2b sentinel ----------
__global__ __launch_bounds__(256) void init_kernel(int* __restrict__ bucket_cursor,
                                                   const float* __restrict__ W1,
                                                   unsigned short* __restrict__ w1t,
                                                   unsigned short* __restrict__ h2b,
                                                   int N, int NB) {
    int tid = threadIdx.x;
    for (int i = tid; i < NB; i += 256) bucket_cursor[i] = 0;
    for (int i = tid; i < F_IN * HID; i += 256) {
        int k = i >> 6, n = i & 63;
        w1t[n * F_IN + k] = f2bf(W1[i]);
    }
    if (tid < NCLS) h2b[(size_t)N * NCLS + tid] = 0;   // zero sentinel row for agg2
}

// ---------- pass 1: self-reserving partition into FIXED-capacity buckets ----------
// part[b*CAP + ofs]. Within-bucket order is arrival order — csr_gemm sorts by node.
__global__ __launch_bounds__(256) void scatter_kernel(const int* __restrict__ src,
                                                      const int* __restrict__ dst,
                                                      int* __restrict__ bucket_cursor,
                                                      unsigned int* __restrict__ part,
                                                      int E, int NB) {
    __shared__ int cnt[NB_MAX];
    __shared__ int cur[NB_MAX];
    int tid = threadIdx.x;
    int blk = blockIdx.x;
    for (int i = tid; i < NB; i += 256) cnt[i] = 0;
    __syncthreads();
    int cb = blk * CHUNK;
    #pragma unroll
    for (int k = 0; k < CHUNK / 1024; k++) {   // pass A: count own chunk
        int e = cb + (k * 256 + tid) * 4;
        if (e + 3 < E) {
            int4 d4 = *(const int4*)&dst[e];
            atomicAdd(&cnt[d4.x >> BSHIFT], 1);
            atomicAdd(&cnt[d4.y >> BSHIFT], 1);
            atomicAdd(&cnt[d4.z >> BSHIFT], 1);
            atomicAdd(&cnt[d4.w >> BSHIFT], 1);
        } else {
            for (int t = 0; t < 4; t++)
                if (e + t < E) atomicAdd(&cnt[dst[e + t] >> BSHIFT], 1);
        }
    }
    __syncthreads();
    for (int i = tid; i < NB; i += 256) {       // reserve ranges in fixed slots
        int c = cnt[i];
        cur[i] = i * CAP + (c ? atomicAdd(&bucket_cursor[i], c) : 0);
    }
    __syncthreads();
    #pragma unroll
    for (int k = 0; k < CHUNK / 1024; k++) {   // pass B: scatter (dst re-read L2-hot)
        int e = cb + (k * 256 + tid) * 4;
        if (e + 3 < E) {
            int4 d4 = *(const int4*)&dst[e];
            int4 s4 = *(const int4*)&src[e];
            int p0 = atomicAdd(&cur[d4.x >> BSHIFT], 1);
            part[p0] = ((unsigned int)(d4.x & (BNODES - 1)) << 24) | (unsigned int)s4.x;
            int p1 = atomicAdd(&cur[d4.y >> BSHIFT], 1);
            part[p1] = ((unsigned int)(d4.y & (BNODES - 1)) << 24) | (unsigned int)s4.y;
            int p2 = atomicAdd(&cur[d4.z >> BSHIFT], 1);
            part[p2] = ((unsigned int)(d4.z & (BNODES - 1)) << 24) | (unsigned int)s4.z;
            int p3 = atomicAdd(&cur[d4.w >> BSHIFT], 1);
            part[p3] = ((unsigned int)(d4.w & (BNODES - 1)) << 24) | (unsigned int)s4.w;
        } else {
            for (int t = 0; t < 4; t++)
                if (e + t < E) {
                    int d = dst[e + t];
                    int pos = atomicAdd(&cur[d >> BSHIFT], 1);
                    part[pos] = ((unsigned int)(d & (BNODES - 1)) << 24) | (unsigned int)src[e + t];
                }
        }
    }
}

// ---------- fused pass 2: per-bucket counting sort -> padded CSR, THEN gemm1 for the
// bucket's own 256 rows. ALIAS SAFETY: block b's h1b rows [b*256,(b+1)*256) occupy ints
// [b*8192,(b+1)*8192) == exactly its own part[] slot, consumed in phase 1 first. ----------
__global__ __launch_bounds__(512) void csr_gemm(const unsigned int* __restrict__ part,
                                                const int* __restrict__ bucket_cursor,
                                                int* __restrict__ csr_src,
                                                int4* __restrict__ rowmeta,
                                                const float* __restrict__ x,
                                                const unsigned short* __restrict__ w1t,
                                                unsigned short* __restrict__ h1b,
                                                int N, int NB) {
    __shared__ union {
        struct {
            unsigned int eL[CAP];
            unsigned int outL[CAP + PADB];
            int cnt[BNODES];
            int sc[BNODES];
            int cur[BNODES];
        } p1;
        struct {
            unsigned short xs[2][64][136];
            unsigned short wsb[64][136];
            float diss[BNODES];
        } p2;
    } u;
    int tid = threadIdx.x;
    int b = blockIdx.x;

    // ================= phase 1: counting sort (round-15 csr_build, verbatim) =========
    int eB = b * CAP;               // fixed part slot
    int eN = bucket_cursor[b];      // final cursor = bucket count
    if (eN > CAP) eN = CAP;
    int pb = b * CAPP;              // fixed csr slot (CAPP multiple of 4 -> aligned)

    if (tid < BNODES) u.p1.cnt[tid] = 0;
    __syncthreads();
    for (int i = tid; i < eN; i += 512) {
        unsigned int v = part[eB + i];
        u.p1.eL[i] = v;
        atomicAdd(&u.p1.cnt[v >> 24], 1);
    }
    for (int i = tid; i < eN + PADB; i += 512) u.p1.outL[i] = (unsigned int)N;
    __syncthreads();
    int myc = 0, pd = 0;
    float dv = 0.f;
    if (tid < BNODES) {
        myc = u.p1.cnt[tid];
        pd = (myc + 3) & ~3;        // padded row length (multiple of 4)
        u.p1.sc[tid] = pd;
    }
    __syncthreads();
    for (int off = 1; off < 256; off <<= 1) {
        int t = (tid >= off && tid < BNODES) ? u.p1.sc[tid - off] : 0;
        __syncthreads();
        if (tid < BNODES) u.p1.sc[tid] += t;
        __syncthreads();
    }
    if (tid < BNODES) {
        int excl = u.p1.sc[tid] - pd;   // multiple of 4
        u.p1.cur[tid] = excl;
        int gnode = b * BNODES + tid;
        if (gnode < N) {
            float d = (float)myc;
            dv = d > 0.0f ? rsqrtf(fmaxf(d, 1.0f)) : 0.0f;
            rowmeta[gnode] = make_int4(pb + excl, pd, __float_as_int(dv), 0);
        }
    }
    __syncthreads();
    int pTot = u.p1.sc[BNODES - 1];
    for (int i = tid; i < eN; i += 512) {
        unsigned int v = u.p1.eL[i];
        int pos = atomicAdd(&u.p1.cur[v >> 24], 1);
        u.p1.outL[pos] = v & 0xFFFFFFu;
    }
    __syncthreads();
    for (int i = tid; i < pTot; i += 512)
        csr_src[pb + i] = (int)u.p1.outL[i];
    __syncthreads();               // phase boundary: all p1 LDS reads done

    // ================= phase 2: gemm for rows [b*256, b*256+256) =====================
    // stage diss (register dv from phase 1) + wsb (w1t, L2-hot)
    if (tid < BNODES) u.p2.diss[tid] = dv;
    #pragma unroll
    for (int it = 0; it < 2; it++) {
        int f = it * 512 + tid;
        int r = f >> 4, c = f & 15;
        *(uint4*)&u.p2.wsb[r][c * 8] = ((const uint4*)w1t)[f];
    }
    if (b == NB - 1 && tid < 8)    // h1b sentinel row N (inside own consumed slot)
        ((uint4*)&h1b[(size_t)N * HID])[tid] = make_uint4(0, 0, 0, 0);
    __syncthreads();

    int g = tid >> 8;              // wave-group 0/1 (each 4 waves, one 64-row subtile)
    int gt = tid & 255;
    int wv = gt >> 6;              // wave within group
    int lane = gt & 63;
    int q = lane >> 4;
    int l15 = lane & 15;
    #pragma unroll
    for (int it2 = 0; it2 < 2; it2++) {
        int st = g + it2 * 2;      // subtile 0..3
        int row0 = b * BNODES + st * 64;
        #pragma unroll
        for (int it = 0; it < 8; it++) {
            int f = it * 256 + gt;
            int r = f >> 5, c = f & 31;
            float4 v = make_float4(0.f, 0.f, 0.f, 0.f);
            if (row0 + r < N) v = ((const float4*)x)[(size_t)(row0 + r) * 32 + c];
            unsigned int p0 = (unsigned int)f2bf(v.x) | ((unsigned int)f2bf(v.y) << 16);
            unsigned int p1 = (unsigned int)f2bf(v.z) | ((unsigned int)f2bf(v.w) << 16);
            *(uint2*)&u.p2.xs[g][r][c * 4] = make_uint2(p0, p1);
        }
        __syncthreads();
        f32x4 acc[4] = {{0,0,0,0},{0,0,0,0},{0,0,0,0},{0,0,0,0}};
        bf16x8 a[4];
        #pragma unroll
        for (int kk = 0; kk < 4; kk++)
            a[kk] = *(const bf16x8*)&u.p2.xs[g][wv * 16 + l15][kk * 32 + q * 8];
        #pragma unroll
        for (int kk = 0; kk < 4; kk++) {
            #pragma unroll
            for (int ct = 0; ct < 4; ct++) {
                bf16x8 bb = *(const bf16x8*)&u.p2.wsb[ct * 16 + l15][kk * 32 + q * 8];
                acc[ct] = __builtin_amdgcn_mfma_f32_16x16x32_bf16(a[kk], bb, acc[ct], 0, 0, 0);
            }
        }
        __syncthreads();
        #pragma unroll
        for (int ct = 0; ct < 4; ct++) {
            #pragma unroll
            for (int r = 0; r < 4; r++) {
                int m = wv * 16 + q * 4 + r;
                u.p2.xs[g][m][ct * 16 + l15] = f2bf(acc[ct][r] * u.p2.diss[st * 64 + m]);
            }
        }
        __syncthreads();
        #pragma unroll
        for (int it = 0; it < 2; it++) {
            int f = it * 256 + gt;
            int r = f >> 3, c = f & 7;
            if (row0 + r < N)
                ((uint4*)&h1b[(size_t)(row0 + r) * HID])[c] = *(const uint4*)&u.p2.xs[g][r][c * 8];
        }
        __syncthreads();           // before next subtile restage
    }
}

// ---------- fused layer-1 agg + ReLU + W2 GEMM ----------
// 4 nodes/wave (16 lanes each: 2 slots x 8 dim-subs); batch-16 + int4 residual loop.
__global__ __launch_bounds__(256) void agg1_fused(
        const int4* __restrict__ rowmeta, const int* __restrict__ csr_src,
        const unsigned short* __restrict__ h1b,
        const float* __restrict__ b1, const float* __restrict__ W2,
        unsigned short* __restrict__ h2b, int N) {
    __shared__ float W2t[NCLS][HID + 4];   // transposed, padded row stride 68
    __shared__ float ts[16][HID];
    int tid = threadIdx.x;
    int w = tid >> 6;
    int lane = tid & 63;
    int quarter = lane >> 4;   // node within wave (0..3)
    int ql = lane & 15;        // lane within node group
    int sub = ql & 7;          // dims sub*8 .. sub*8+7 (16B)
    int slot = ql >> 3;        // edge slot 0..1 (each owns 2 int4 runs = 8 edges)
    int nb = w * 4 + quarter;  // node within block (0..15)
    int n = blockIdx.x * 16 + nb;
    int nc = (n < N) ? n : 0;  // clamp so tail lanes still load safely

    int4 meta = rowmeta[nc];
    int start = meta.x;        // 4-aligned by construction
    int plen = meta.y;         // multiple of 4
    float dn = __int_as_float(meta.z);
    const int4* ip = (const int4*)(csr_src + start);
    int4 q0 = ip[2 * slot];
    int4 q1 = ip[2 * slot + 1];

    for (int i = tid; i < HID * NCLS; i += 256) W2t[i & 15][i >> 4] = W2[i];
    __syncthreads();
    if (n >= N) return;        // after the only __syncthreads (no barrier below)

    int e0 = slot * 8;
    if (e0 >= plen)     q0 = make_int4(N, N, N, N);
    if (e0 + 4 >= plen) q1 = make_int4(N, N, N, N);
    const unsigned short* hp = h1b + sub * 8;
    uint4 v0 = *(const uint4*)(hp + (unsigned)q0.x * HID);
    uint4 v1 = *(const uint4*)(hp + (unsigned)q0.y * HID);
    uint4 v2 = *(const uint4*)(hp + (unsigned)q0.z * HID);
    uint4 v3 = *(const uint4*)(hp + (unsigned)q0.w * HID);
    uint4 v4 = *(const uint4*)(hp + (unsigned)q1.x * HID);
    uint4 v5 = *(const uint4*)(hp + (unsigned)q1.y * HID);
    uint4 v6 = *(const uint4*)(hp + (unsigned)q1.z * HID);
    uint4 v7 = *(const uint4*)(hp + (unsigned)q1.w * HID);
    f32x2 a0 = (bfpair(v0.x) + bfpair(v1.x)) + (bfpair(v2.x) + bfpair(v3.x));
    f32x2 a1 = (bfpair(v0.y) + bfpair(v1.y)) + (bfpair(v2.y) + bfpair(v3.y));
    f32x2 a2 = (bfpair(v0.z) + bfpair(v1.z)) + (bfpair(v2.z) + bfpair(v3.z));
    f32x2 a3 = (bfpair(v0.w) + bfpair(v1.w)) + (bfpair(v2.w) + bfpair(v3.w));
    a0 += (bfpair(v4.x) + bfpair(v5.x)) + (bfpair(v6.x) + bfpair(v7.x));
    a1 += (bfpair(v4.y) + bfpair(v5.y)) + (bfpair(v6.y) + bfpair(v7.y));
    a2 += (bfpair(v4.z) + bfpair(v5.z)) + (bfpair(v6.z) + bfpair(v7.z));
    a3 += (bfpair(v4.w) + bfpair(v5.w)) + (bfpair(v6.w) + bfpair(v7.w));
    // residual: slots alternate int4 runs past edge 16 (~55% of rows; exec-masked)
    for (int i4 = 4 + slot; i4 * 4 < plen; i4 += 2) {
        int4 qq = ip[i4];
        uint4 r0 = *(const uint4*)(hp + (unsigned)qq.x * HID);
        uint4 r1 = *(const uint4*)(hp + (unsigned)qq.y * HID);
        uint4 r2 = *(const uint4*)(hp + (unsigned)qq.z * HID);
        uint4 r3 = *(const uint4*)(hp + (unsigned)qq.w * HID);
        a0 += (bfpair(r0.x) + bfpair(r1.x)) + (bfpair(r2.x) + bfpair(r3.x));
        a1 += (bfpair(r0.y) + bfpair(r1.y)) + (bfpair(r2.y) + bfpair(r3.y));
        a2 += (bfpair(r0.z) + bfpair(r1.z)) + (bfpair(r2.z) + bfpair(r3.z));
        a3 += (bfpair(r0.w) + bfpair(r1.w)) + (bfpair(r2.w) + bfpair(r3.w));
    }
    // reduce across the 2 slots (lane bit 3 — stays within the node group)
    a0.x += __shfl_xor(a0.x, 8, 64); a0.y += __shfl_xor(a0.y, 8, 64);
    a1.x += __shfl_xor(a1.x, 8, 64); a1.y += __shfl_xor(a1.y, 8, 64);
    a2.x += __shfl_xor(a2.x, 8, 64); a2.y += __shfl_xor(a2.y, 8, 64);
    a3.x += __shfl_xor(a3.x, 8, 64); a3.y += __shfl_xor(a3.y, 8, 64);
    if (slot == 0) {
        float4 bl = ((const float4*)b1)[sub * 2];
        float4 bh = ((const float4*)b1)[sub * 2 + 1];
        float4 r0, r1;
        r0.x = fmaxf(fmaf(dn, a0.x, bl.x), 0.f);
        r0.y = fmaxf(fmaf(dn, a0.y, bl.y), 0.f);
        r0.z = fmaxf(fmaf(dn, a1.x, bl.z), 0.f);
        r0.w = fmaxf(fmaf(dn, a1.y, bl.w), 0.f);
        r1.x = fmaxf(fmaf(dn, a2.x, bh.x), 0.f);
        r1.y = fmaxf(fmaf(dn, a2.y, bh.y), 0.f);
        r1.z = fmaxf(fmaf(dn, a3.x, bh.z), 0.f);
        r1.w = fmaxf(fmaf(dn, a3.y, bh.w), 0.f);
        *(float4*)&ts[nb][sub * 8] = r0;
        *(float4*)&ts[nb][sub * 8 + 4] = r1;
    }
    // wave-local LDS round-trip; each of 16 lanes owns one output class (no shuffle)
    int c = ql;
    const float* tp = &ts[nb][0];
    const float* wp = &W2t[c][0];
    float p = 0.f;
    #pragma unroll
    for (int j = 0; j < 16; j++) {
        float4 tt = *(const float4*)(tp + j * 4);
        float4 uu = *(const float4*)(wp + j * 4);
        p += tt.x * uu.x + tt.y * uu.y + tt.z * uu.z + tt.w * uu.w;
    }
    h2b[(unsigned)n * NCLS + c] = f2bf(p * dn);
}

// ---------- fused layer-2 agg + epilogue ----------
// 8 nodes/wave (8 lanes each: 4 slots x 2 dim-subs); batch-16 + int4 residual loop
__global__ __launch_bounds__(256) void agg2_fused(
        const int4* __restrict__ rowmeta, const int* __restrict__ csr_src,
        const unsigned short* __restrict__ h2b,
        const float* __restrict__ b2, float* __restrict__ out, int N) {
    int t = blockIdx.x * 256 + threadIdx.x;
    int lane = t & 63;
    int grp = lane >> 3;         // node within wave (0..7)
    int gl = lane & 7;
    int slot = gl >> 1;          // edge slot 0..3 (each owns 1 int4 = 4 edges)
    int sub = gl & 1;            // dims sub*8 .. sub*8+7
    int n = (t >> 6) * 8 + grp;
    if (n >= N) return;          // uniform within each 8-lane group
    int4 meta = rowmeta[n];
    int start = meta.x;
    int plen = meta.y;
    float dn = __int_as_float(meta.z);
    const int4* ip = (const int4*)(csr_src + start);
    int4 q0 = ip[slot];
    int e0 = slot * 4;
    if (e0 >= plen) q0 = make_int4(N, N, N, N);   // plen mult of 4: all-or-nothing
    const unsigned short* hp = h2b + sub * 8;
    uint4 v0 = *(const uint4*)(hp + (unsigned)q0.x * NCLS);
    uint4 v1 = *(const uint4*)(hp + (unsigned)q0.y * NCLS);
    uint4 v2 = *(const uint4*)(hp + (unsigned)q0.z * NCLS);
    uint4 v3 = *(const uint4*)(hp + (unsigned)q0.w * NCLS);
    f32x2 a0 = (bfpair(v0.x) + bfpair(v1.x)) + (bfpair(v2.x) + bfpair(v3.x));
    f32x2 a1 = (bfpair(v0.y) + bfpair(v1.y)) + (bfpair(v2.y) + bfpair(v3.y));
    f32x2 a2 = (bfpair(v0.z) + bfpair(v1.z)) + (bfpair(v2.z) + bfpair(v3.z));
    f32x2 a3 = (bfpair(v0.w) + bfpair(v1.w)) + (bfpair(v2.w) + bfpair(v3.w));
    // residual: slots alternate int4 runs past edge 16 (exec-masked)
    for (int i4 = 4 + slot; i4 * 4 < plen; i4 += 4) {
        int4 qq = ip[i4];
        uint4 r0 = *(const uint4*)(hp + (unsigned)qq.x * NCLS);
        uint4 r1 = *(const uint4*)(hp + (unsigned)qq.y * NCLS);
        uint4 r2 = *(const uint4*)(hp + (unsigned)qq.z * NCLS);
        uint4 r3 = *(const uint4*)(hp + (unsigned)qq.w * NCLS);
        a0 += (bfpair(r0.x) + bfpair(r1.x)) + (bfpair(r2.x) + bfpair(r3.x));
        a1 += (bfpair(r0.y) + bfpair(r1.y)) + (bfpair(r2.y) + bfpair(r3.y));
        a2 += (bfpair(r0.z) + bfpair(r1.z)) + (bfpair(r2.z) + bfpair(r3.z));
        a3 += (bfpair(r0.w) + bfpair(r1.w)) + (bfpair(r2.w) + bfpair(r3.w));
    }
    // reduce across 4 slots (lane bits 1,2 — stays inside the 8-lane group)
    #pragma unroll
    for (int m = 2; m <= 4; m <<= 1) {
        a0.x += __shfl_xor(a0.x, m, 64); a0.y += __shfl_xor(a0.y, m, 64);
        a1.x += __shfl_xor(a1.x, m, 64); a1.y += __shfl_xor(a1.y, m, 64);
        a2.x += __shfl_xor(a2.x, m, 64); a2.y += __shfl_xor(a2.y, m, 64);
        a3.x += __shfl_xor(a3.x, m, 64); a3.y += __shfl_xor(a3.y, m, 64);
    }
    if (slot == 0) {
        float4 bl = ((const float4*)b2)[sub * 2];
        float4 bh = ((const float4*)b2)[sub * 2 + 1];
        float4 o0, o1;
        o0.x = fmaf(dn, a0.x, bl.x); o0.y = fmaf(dn, a0.y, bl.y);
        o0.z = fmaf(dn, a1.x, bl.z); o0.w = fmaf(dn, a1.y, bl.w);
        o1.x = fmaf(dn, a2.x, bh.x); o1.y = fmaf(dn, a2.y, bh.y);
        o1.z = fmaf(dn, a3.x, bh.z); o1.w = fmaf(dn, a3.y, bh.w);
        float* op = out + (unsigned)n * NCLS + sub * 8;
        *(float4*)op = o0;
        *(float4*)(op + 4) = o1;
    }
}

extern "C" void kernel_launch(void* const* d_in, const int* in_sizes, int n_in,
                              void* d_out, int out_size, void* d_ws, size_t ws_size,
                              hipStream_t stream) {
    const float* x   = (const float*)d_in[0];
    const int*   src = (const int*)  d_in[1];
    const int*   dst = (const int*)  d_in[2];
    const float* W1  = (const float*)d_in[3];
    const float* b1  = (const float*)d_in[4];
    const float* W2  = (const float*)d_in[5];
    const float* b2  = (const float*)d_in[6];
    float* out = (float*)d_out;
    int E = in_sizes[1];
    int N = in_sizes[0] / F_IN;
    int NB = (N + BNODES - 1) >> BSHIFT;
    int nchunks = (E + CHUNK - 1) / CHUNK;   // 208 for E=1.7M

    char* ws = (char*)d_ws;
    size_t off = 0;
    auto alloc = [&](size_t bytes) { size_t o = off; off = (off + bytes + 255) & ~(size_t)255; return (void*)(ws + o); };
    int*   bucket_cursor = (int*)  alloc((size_t)NB * 4);
    int4*  rowmeta       = (int4*) alloc((size_t)N * 16);
    int*   csr_src       = (int*)  alloc((size_t)NB * CAPP * 4);   // fixed-stride padded CSR
    unsigned short* w1t  = (unsigned short*)alloc((size_t)F_IN * HID * 2);
    size_t h1b_bytes  = (size_t)(N + 1) * HID * 2;                 // 12.80 MB
    size_t part_bytes = (size_t)NB * CAP * 4;                      // 12.81 MB
    unsigned short* h1b  = (unsigned short*)alloc(h1b_bytes > part_bytes ? h1b_bytes : part_bytes);
    unsigned short* h2b  = (unsigned short*)alloc((size_t)(N + 1) * NCLS * 2); // +1 sentinel row
    // part[] aliases h1b: each csr_gemm block consumes its part slot (phase 1) before
    // writing the SAME ints as its h1b rows (phase 2) — race-free by construction.
    unsigned int* part   = (unsigned int*)h1b;

    init_kernel    <<<1, 256, 0, stream>>>(bucket_cursor, W1, w1t, h2b, N, NB);
    scatter_kernel <<<nchunks, 256, 0, stream>>>(src, dst, bucket_cursor, part, E, NB);
    csr_gemm       <<<NB, 512, 0, stream>>>(part, bucket_cursor, csr_src, rowmeta, x, w1t, h1b, N, NB);
    agg1_fused     <<<(N + 15) / 16, 256, 0, stream>>>(rowmeta, csr_src, h1b, b1, W2, h2b, N);
    agg2_fused     <<<(N + 31) / 32, 256, 0, stream>>>(rowmeta, csr_src, h2b, b2, out, N);
}

// Round 17
// 190.479 us; speedup vs baseline: 1.0343x; 1.0343x over previous
//
#include <hip/hip_runtime.h>

#define F_IN 128
#define HID  64
#define NCLS 16

#define BSHIFT 8            // 256 nodes per bucket
#define BNODES 256
#define NB_MAX 512          // max buckets (N<=128k)
#define CHUNK  8192         // edges per partition block
#define CAP    8192         // fixed part[] slot per bucket (mean 4352, 50+ sigma margin)
#define PADB   772          // csr per-bucket padding slack: 256 rows * 3 + align
#define CAPP   (CAP + PADB) // fixed csr slot per bucket (8964, multiple of 4)

typedef __attribute__((ext_vector_type(2))) float f32x2;
typedef __attribute__((ext_vector_type(8))) short bf16x8;
typedef __attribute__((ext_vector_type(4))) float f32x4;

// round-to-nearest-even fp32 -> bf16
__device__ __forceinline__ unsigned short f2bf(float f) {
    unsigned int u = __float_as_uint(f);
    u += 0x7FFFu + ((u >> 16) & 1u);
    return (unsigned short)(u >> 16);
}
// one dword = 2 packed bf16 -> f32x2 (2 VALU unpack + packed add)
// NOTE: do NOT replace with __builtin_amdgcn_fdot2_f32_bf16 — it compiles on
// gfx950 but produces wrong numerics (round-9 failure, absmax 0.57).
__device__ __forceinline__ f32x2 bfpair(unsigned int u) {
    f32x2 r;
    r.x = __uint_as_float(u << 16);
    r.y = __uint_as_float(u & 0xFFFF0000u);
    return r;
}

// ---------- init (1 block): zero cursors + w1t conversion + h2b sentinel ----------
__global__ __launch_bounds__(256) void init_kernel(int* __restrict__ bucket_cursor,
                                                   const float* __restrict__ W1,
                                                   unsigned short* __restrict__ w1t,
                                                   unsigned short* __restrict__ h2b,
                                                   int N, int NB) {
    int tid = threadIdx.x;
    for (int i = tid; i < NB; i += 256) bucket_cursor[i] = 0;
    for (int i = tid; i < F_IN * HID; i += 256) {
        int k = i >> 6, n = i & 63;
        w1t[n * F_IN + k] = f2bf(W1[i]);
    }
    if (tid < NCLS) h2b[(size_t)N * NCLS + tid] = 0;   // zero sentinel row for agg2
}

// ---------- pass 1: self-reserving partition into FIXED-capacity buckets ----------
// part[b*CAP + ofs]. Within-bucket order is arrival order — csr_build sorts by node.
__global__ __launch_bounds__(256) void scatter_kernel(const int* __restrict__ src,
                                                      const int* __restrict__ dst,
                                                      int* __restrict__ bucket_cursor,
                                                      unsigned int* __restrict__ part,
                                                      int E, int NB) {
    __shared__ int cnt[NB_MAX];
    __shared__ int cur[NB_MAX];
    int tid = threadIdx.x;
    int blk = blockIdx.x;
    for (int i = tid; i < NB; i += 256) cnt[i] = 0;
    __syncthreads();
    int cb = blk * CHUNK;
    #pragma unroll
    for (int k = 0; k < CHUNK / 1024; k++) {   // pass A: count own chunk
        int e = cb + (k * 256 + tid) * 4;
        if (e + 3 < E) {
            int4 d4 = *(const int4*)&dst[e];
            atomicAdd(&cnt[d4.x >> BSHIFT], 1);
            atomicAdd(&cnt[d4.y >> BSHIFT], 1);
            atomicAdd(&cnt[d4.z >> BSHIFT], 1);
            atomicAdd(&cnt[d4.w >> BSHIFT], 1);
        } else {
            for (int t = 0; t < 4; t++)
                if (e + t < E) atomicAdd(&cnt[dst[e + t] >> BSHIFT], 1);
        }
    }
    __syncthreads();
    for (int i = tid; i < NB; i += 256) {       // reserve ranges in fixed slots
        int c = cnt[i];
        cur[i] = i * CAP + (c ? atomicAdd(&bucket_cursor[i], c) : 0);
    }
    __syncthreads();
    #pragma unroll
    for (int k = 0; k < CHUNK / 1024; k++) {   // pass B: scatter (dst re-read L2-hot)
        int e = cb + (k * 256 + tid) * 4;
        if (e + 3 < E) {
            int4 d4 = *(const int4*)&dst[e];
            int4 s4 = *(const int4*)&src[e];
            int p0 = atomicAdd(&cur[d4.x >> BSHIFT], 1);
            part[p0] = ((unsigned int)(d4.x & (BNODES - 1)) << 24) | (unsigned int)s4.x;
            int p1 = atomicAdd(&cur[d4.y >> BSHIFT], 1);
            part[p1] = ((unsigned int)(d4.y & (BNODES - 1)) << 24) | (unsigned int)s4.y;
            int p2 = atomicAdd(&cur[d4.z >> BSHIFT], 1);
            part[p2] = ((unsigned int)(d4.z & (BNODES - 1)) << 24) | (unsigned int)s4.z;
            int p3 = atomicAdd(&cur[d4.w >> BSHIFT], 1);
            part[p3] = ((unsigned int)(d4.w & (BNODES - 1)) << 24) | (unsigned int)s4.w;
        } else {
            for (int t = 0; t < 4; t++)
                if (e + t < E) {
                    int d = dst[e + t];
                    int pos = atomicAdd(&cur[d >> BSHIFT], 1);
                    part[pos] = ((unsigned int)(d & (BNODES - 1)) << 24) | (unsigned int)src[e + t];
                }
        }
    }
}

// ---------- pass 2: per-bucket counting sort -> PADDED csr at fixed stride b*CAPP ----------
// 512 threads: halves every stride loop vs 256 (LDS 71KB -> still 2 blocks/CU)
__global__ __launch_bounds__(512) void csr_build(const unsigned int* __restrict__ part,
                                                 const int* __restrict__ bucket_cursor,
                                                 int* __restrict__ csr_src,
                                                 int4* __restrict__ rowmeta,
                                                 float* __restrict__ dis,
                                                 int N) {
    __shared__ unsigned int eL[CAP];
    __shared__ unsigned int outL[CAP + PADB];
    __shared__ int cnt[BNODES];
    __shared__ int sc[BNODES];
    __shared__ int cur[BNODES];
    int tid = threadIdx.x;
    int b = blockIdx.x;
    int eB = b * CAP;               // fixed part slot
    int eN = bucket_cursor[b];      // final cursor = bucket count
    if (eN > CAP) eN = CAP;
    int pb = b * CAPP;              // fixed csr slot (CAPP multiple of 4 -> aligned)

    if (tid < BNODES) cnt[tid] = 0;
    __syncthreads();
    for (int i = tid; i < eN; i += 512) {
        unsigned int v = part[eB + i];
        eL[i] = v;
        atomicAdd(&cnt[v >> 24], 1);
    }
    // sentinel-init the padded output region (real edges overwrite below)
    for (int i = tid; i < eN + PADB; i += 512) outL[i] = (unsigned int)N;
    __syncthreads();
    int myc = 0, pd = 0;
    if (tid < BNODES) {
        myc = cnt[tid];
        pd = (myc + 3) & ~3;        // padded row length (multiple of 4)
        sc[tid] = pd;
    }
    __syncthreads();
    for (int off = 1; off < 256; off <<= 1) {
        int t = (tid >= off && tid < BNODES) ? sc[tid - off] : 0;
        __syncthreads();
        if (tid < BNODES) sc[tid] += t;
        __syncthreads();
    }
    if (tid < BNODES) {
        int excl = sc[tid] - pd;    // multiple of 4
        cur[tid] = excl;
        int gnode = b * BNODES + tid;
        if (gnode < N) {
            float d = (float)myc;
            float dv = d > 0.0f ? rsqrtf(fmaxf(d, 1.0f)) : 0.0f;
            rowmeta[gnode] = make_int4(pb + excl, pd, __float_as_int(dv), 0);
            dis[gnode] = dv;
        }
    }
    __syncthreads();
    int pTot = sc[BNODES - 1];      // padded bucket total (<= eN + PADB)
    for (int i = tid; i < eN; i += 512) {
        unsigned int v = eL[i];
        int pos = atomicAdd(&cur[v >> 24], 1);
        outL[pos] = v & 0xFFFFFFu;
    }
    __syncthreads();
    for (int i = tid; i < pTot; i += 512)
        csr_src[pb + i] = (int)outL[i];
}

// ---------- gemm1 via MFMA bf16: 64 rows/block; also emits zeroed sentinel row N ----------
__global__ __launch_bounds__(256) void gemm1_kernel(
        const float* __restrict__ x, const unsigned short* __restrict__ w1t,
        const float* __restrict__ dis, unsigned short* __restrict__ h1b, int N) {
    __shared__ unsigned short xs[64][136];
    __shared__ unsigned short wsb[64][136];
    __shared__ float diss[64];
    int tid = threadIdx.x;
    int w = tid >> 6;
    int lane = tid & 63;
    int row0 = blockIdx.x * 64;

    #pragma unroll
    for (int it = 0; it < 8; it++) {
        int f = it * 256 + tid;
        int r = f >> 5, c = f & 31;
        float4 v = make_float4(0.f, 0.f, 0.f, 0.f);
        if (row0 + r < N) v = ((const float4*)x)[(size_t)(row0 + r) * 32 + c];
        unsigned int p0 = (unsigned int)f2bf(v.x) | ((unsigned int)f2bf(v.y) << 16);
        unsigned int p1 = (unsigned int)f2bf(v.z) | ((unsigned int)f2bf(v.w) << 16);
        *(uint2*)&xs[r][c * 4] = make_uint2(p0, p1);
    }
    #pragma unroll
    for (int it = 0; it < 4; it++) {
        int f = it * 256 + tid;
        int r = f >> 4, c = f & 15;
        *(uint4*)&wsb[r][c * 8] = ((const uint4*)w1t)[f];
    }
    if (tid < 64) diss[tid] = (row0 + tid < N) ? dis[row0 + tid] : 0.f;
    __syncthreads();

    int q = lane >> 4;
    int l15 = lane & 15;
    f32x4 acc[4] = {{0,0,0,0},{0,0,0,0},{0,0,0,0},{0,0,0,0}};
    bf16x8 a[4];
    #pragma unroll
    for (int kk = 0; kk < 4; kk++)
        a[kk] = *(const bf16x8*)&xs[w * 16 + l15][kk * 32 + q * 8];
    #pragma unroll
    for (int kk = 0; kk < 4; kk++) {
        #pragma unroll
        for (int ct = 0; ct < 4; ct++) {
            bf16x8 b = *(const bf16x8*)&wsb[ct * 16 + l15][kk * 32 + q * 8];
            acc[ct] = __builtin_amdgcn_mfma_f32_16x16x32_bf16(a[kk], b, acc[ct], 0, 0, 0);
        }
    }
    __syncthreads();
    #pragma unroll
    for (int ct = 0; ct < 4; ct++) {
        #pragma unroll
        for (int r = 0; r < 4; r++) {
            int m = w * 16 + q * 4 + r;
            xs[m][ct * 16 + l15] = f2bf(acc[ct][r] * diss[m]);
        }
    }
    __syncthreads();
    #pragma unroll
    for (int it = 0; it < 2; it++) {
        int f = it * 256 + tid;
        int r = f >> 3, c = f & 7;
        if (row0 + r < N + 1)   // row N written as zeros (diss=0) -> gather sentinel
            ((uint4*)&h1b[(size_t)(row0 + r) * HID])[c] = *(const uint4*)&xs[r][c * 8];
    }
}

// ---------- fused layer-1 agg + ReLU + W2 GEMM ----------
// 4 nodes/wave (16 lanes each: 2 slots x 8 dim-subs); batch-16 + int4 residual loop.
// Per lane: 1 rowmeta + 2 idx loads + 8 gathers (batch) + residual; shuffle-free dot.
__global__ __launch_bounds__(256) void agg1_fused(
        const int4* __restrict__ rowmeta, const int* __restrict__ csr_src,
        const unsigned short* __restrict__ h1b,
        const float* __restrict__ b1, const float* __restrict__ W2,
        unsigned short* __restrict__ h2b, int N) {
    __shared__ float W2t[NCLS][HID + 4];   // transposed, padded row stride 68
    __shared__ float ts[16][HID];
    int tid = threadIdx.x;
    int w = tid >> 6;
    int lane = tid & 63;
    int quarter = lane >> 4;   // node within wave (0..3)
    int ql = lane & 15;        // lane within node group
    int sub = ql & 7;          // dims sub*8 .. sub*8+7 (16B)
    int slot = ql >> 3;        // edge slot 0..1 (each owns 2 int4 runs = 8 edges)
    int nb = w * 4 + quarter;  // node within block (0..15)
    int n = blockIdx.x * 16 + nb;
    int nc = (n < N) ? n : 0;  // clamp so tail lanes still load safely

    // single 16B rowmeta load + vector index loads BEFORE LDS staging
    int4 meta = rowmeta[nc];
    int start = meta.x;        // 4-aligned by construction
    int plen = meta.y;         // multiple of 4
    float dn = __int_as_float(meta.z);
    const int4* ip = (const int4*)(csr_src + start);
    int4 q0 = ip[2 * slot];
    int4 q1 = ip[2 * slot + 1];

    for (int i = tid; i < HID * NCLS; i += 256) W2t[i & 15][i >> 4] = W2[i];
    __syncthreads();
    if (n >= N) return;        // after the only __syncthreads (no barrier below)

    // vector sentinel-select: plen % 4 == 0, one compare covers a whole int4
    int e0 = slot * 8;
    if (e0 >= plen)     q0 = make_int4(N, N, N, N);
    if (e0 + 4 >= plen) q1 = make_int4(N, N, N, N);
    const unsigned short* hp = h1b + sub * 8;
    uint4 v0 = *(const uint4*)(hp + (unsigned)q0.x * HID);
    uint4 v1 = *(const uint4*)(hp + (unsigned)q0.y * HID);
    uint4 v2 = *(const uint4*)(hp + (unsigned)q0.z * HID);
    uint4 v3 = *(const uint4*)(hp + (unsigned)q0.w * HID);
    uint4 v4 = *(const uint4*)(hp + (unsigned)q1.x * HID);
    uint4 v5 = *(const uint4*)(hp + (unsigned)q1.y * HID);
    uint4 v6 = *(const uint4*)(hp + (unsigned)q1.z * HID);
    uint4 v7 = *(const uint4*)(hp + (unsigned)q1.w * HID);
    f32x2 a0 = (bfpair(v0.x) + bfpair(v1.x)) + (bfpair(v2.x) + bfpair(v3.x));
    f32x2 a1 = (bfpair(v0.y) + bfpair(v1.y)) + (bfpair(v2.y) + bfpair(v3.y));
    f32x2 a2 = (bfpair(v0.z) + bfpair(v1.z)) + (bfpair(v2.z) + bfpair(v3.z));
    f32x2 a3 = (bfpair(v0.w) + bfpair(v1.w)) + (bfpair(v2.w) + bfpair(v3.w));
    a0 += (bfpair(v4.x) + bfpair(v5.x)) + (bfpair(v6.x) + bfpair(v7.x));
    a1 += (bfpair(v4.y) + bfpair(v5.y)) + (bfpair(v6.y) + bfpair(v7.y));
    a2 += (bfpair(v4.z) + bfpair(v5.z)) + (bfpair(v6.z) + bfpair(v7.z));
    a3 += (bfpair(v4.w) + bfpair(v5.w)) + (bfpair(v6.w) + bfpair(v7.w));
    // residual: slots alternate int4 runs past edge 16 (~55% of rows; exec-masked)
    for (int i4 = 4 + slot; i4 * 4 < plen; i4 += 2) {
        int4 qq = ip[i4];
        uint4 r0 = *(const uint4*)(hp + (unsigned)qq.x * HID);
        uint4 r1 = *(const uint4*)(hp + (unsigned)qq.y * HID);
        uint4 r2 = *(const uint4*)(hp + (unsigned)qq.z * HID);
        uint4 r3 = *(const uint4*)(hp + (unsigned)qq.w * HID);
        a0 += (bfpair(r0.x) + bfpair(r1.x)) + (bfpair(r2.x) + bfpair(r3.x));
        a1 += (bfpair(r0.y) + bfpair(r1.y)) + (bfpair(r2.y) + bfpair(r3.y));
        a2 += (bfpair(r0.z) + bfpair(r1.z)) + (bfpair(r2.z) + bfpair(r3.z));
        a3 += (bfpair(r0.w) + bfpair(r1.w)) + (bfpair(r2.w) + bfpair(r3.w));
    }
    // reduce across the 2 slots (lane bit 3 — stays within the node group)
    a0.x += __shfl_xor(a0.x, 8, 64); a0.y += __shfl_xor(a0.y, 8, 64);
    a1.x += __shfl_xor(a1.x, 8, 64); a1.y += __shfl_xor(a1.y, 8, 64);
    a2.x += __shfl_xor(a2.x, 8, 64); a2.y += __shfl_xor(a2.y, 8, 64);
    a3.x += __shfl_xor(a3.x, 8, 64); a3.y += __shfl_xor(a3.y, 8, 64);
    if (slot == 0) {
        float4 bl = ((const float4*)b1)[sub * 2];
        float4 bh = ((const float4*)b1)[sub * 2 + 1];
        float4 r0, r1;
        r0.x = fmaxf(fmaf(dn, a0.x, bl.x), 0.f);
        r0.y = fmaxf(fmaf(dn, a0.y, bl.y), 0.f);
        r0.z = fmaxf(fmaf(dn, a1.x, bl.z), 0.f);
        r0.w = fmaxf(fmaf(dn, a1.y, bl.w), 0.f);
        r1.x = fmaxf(fmaf(dn, a2.x, bh.x), 0.f);
        r1.y = fmaxf(fmaf(dn, a2.y, bh.y), 0.f);
        r1.z = fmaxf(fmaf(dn, a3.x, bh.z), 0.f);
        r1.w = fmaxf(fmaf(dn, a3.y, bh.w), 0.f);
        *(float4*)&ts[nb][sub * 8] = r0;
        *(float4*)&ts[nb][sub * 8 + 4] = r1;
    }
    // wave-local LDS round-trip; each of 16 lanes owns one output class (no shuffle)
    int c = ql;
    const float* tp = &ts[nb][0];
    const float* wp = &W2t[c][0];
    float p = 0.f;
    #pragma unroll
    for (int j = 0; j < 16; j++) {
        float4 tt = *(const float4*)(tp + j * 4);
        float4 uu = *(const float4*)(wp + j * 4);
        p += tt.x * uu.x + tt.y * uu.y + tt.z * uu.z + tt.w * uu.w;
    }
    h2b[(unsigned)n * NCLS + c] = f2bf(p * dn);
}

// ---------- fused layer-2 agg + epilogue ----------
// 8 nodes/wave (8 lanes each: 4 slots x 2 dim-subs); batch-16 + int4 residual loop
__global__ __launch_bounds__(256) void agg2_fused(
        const int4* __restrict__ rowmeta, const int* __restrict__ csr_src,
        const unsigned short* __restrict__ h2b,
        const float* __restrict__ b2, float* __restrict__ out, int N) {
    int t = blockIdx.x * 256 + threadIdx.x;
    int lane = t & 63;
    int grp = lane >> 3;         // node within wave (0..7)
    int gl = lane & 7;
    int slot = gl >> 1;          // edge slot 0..3 (each owns 1 int4 = 4 edges)
    int sub = gl & 1;            // dims sub*8 .. sub*8+7
    int n = (t >> 6) * 8 + grp;
    if (n >= N) return;          // uniform within each 8-lane group
    int4 meta = rowmeta[n];
    int start = meta.x;
    int plen = meta.y;
    float dn = __int_as_float(meta.z);
    const int4* ip = (const int4*)(csr_src + start);
    int4 q0 = ip[slot];
    int e0 = slot * 4;
    if (e0 >= plen) q0 = make_int4(N, N, N, N);   // plen mult of 4: all-or-nothing
    const unsigned short* hp = h2b + sub * 8;
    uint4 v0 = *(const uint4*)(hp + (unsigned)q0.x * NCLS);
    uint4 v1 = *(const uint4*)(hp + (unsigned)q0.y * NCLS);
    uint4 v2 = *(const uint4*)(hp + (unsigned)q0.z * NCLS);
    uint4 v3 = *(const uint4*)(hp + (unsigned)q0.w * NCLS);
    f32x2 a0 = (bfpair(v0.x) + bfpair(v1.x)) + (bfpair(v2.x) + bfpair(v3.x));
    f32x2 a1 = (bfpair(v0.y) + bfpair(v1.y)) + (bfpair(v2.y) + bfpair(v3.y));
    f32x2 a2 = (bfpair(v0.z) + bfpair(v1.z)) + (bfpair(v2.z) + bfpair(v3.z));
    f32x2 a3 = (bfpair(v0.w) + bfpair(v1.w)) + (bfpair(v2.w) + bfpair(v3.w));
    // residual: slots alternate int4 runs past edge 16 (exec-masked)
    for (int i4 = 4 + slot; i4 * 4 < plen; i4 += 4) {
        int4 qq = ip[i4];
        uint4 r0 = *(const uint4*)(hp + (unsigned)qq.x * NCLS);
        uint4 r1 = *(const uint4*)(hp + (unsigned)qq.y * NCLS);
        uint4 r2 = *(const uint4*)(hp + (unsigned)qq.z * NCLS);
        uint4 r3 = *(const uint4*)(hp + (unsigned)qq.w * NCLS);
        a0 += (bfpair(r0.x) + bfpair(r1.x)) + (bfpair(r2.x) + bfpair(r3.x));
        a1 += (bfpair(r0.y) + bfpair(r1.y)) + (bfpair(r2.y) + bfpair(r3.y));
        a2 += (bfpair(r0.z) + bfpair(r1.z)) + (bfpair(r2.z) + bfpair(r3.z));
        a3 += (bfpair(r0.w) + bfpair(r1.w)) + (bfpair(r2.w) + bfpair(r3.w));
    }
    // reduce across 4 slots (lane bits 1,2 — stays inside the 8-lane group)
    #pragma unroll
    for (int m = 2; m <= 4; m <<= 1) {
        a0.x += __shfl_xor(a0.x, m, 64); a0.y += __shfl_xor(a0.y, m, 64);
        a1.x += __shfl_xor(a1.x, m, 64); a1.y += __shfl_xor(a1.y, m, 64);
        a2.x += __shfl_xor(a2.x, m, 64); a2.y += __shfl_xor(a2.y, m, 64);
        a3.x += __shfl_xor(a3.x, m, 64); a3.y += __shfl_xor(a3.y, m, 64);
    }
    if (slot == 0) {
        float4 bl = ((const float4*)b2)[sub * 2];
        float4 bh = ((const float4*)b2)[sub * 2 + 1];
        float4 o0, o1;
        o0.x = fmaf(dn, a0.x, bl.x); o0.y = fmaf(dn, a0.y, bl.y);
        o0.z = fmaf(dn, a1.x, bl.z); o0.w = fmaf(dn, a1.y, bl.w);
        o1.x = fmaf(dn, a2.x, bh.x); o1.y = fmaf(dn, a2.y, bh.y);
        o1.z = fmaf(dn, a3.x, bh.z); o1.w = fmaf(dn, a3.y, bh.w);
        float* op = out + (unsigned)n * NCLS + sub * 8;
        *(float4*)op = o0;
        *(float4*)(op + 4) = o1;
    }
}

extern "C" void kernel_launch(void* const* d_in, const int* in_sizes, int n_in,
                              void* d_out, int out_size, void* d_ws, size_t ws_size,
                              hipStream_t stream) {
    const float* x   = (const float*)d_in[0];
    const int*   src = (const int*)  d_in[1];
    const int*   dst = (const int*)  d_in[2];
    const float* W1  = (const float*)d_in[3];
    const float* b1  = (const float*)d_in[4];
    const float* W2  = (const float*)d_in[5];
    const float* b2  = (const float*)d_in[6];
    float* out = (float*)d_out;
    int E = in_sizes[1];
    int N = in_sizes[0] / F_IN;
    int NB = (N + BNODES - 1) >> BSHIFT;
    int nchunks = (E + CHUNK - 1) / CHUNK;   // 208 for E=1.7M

    char* ws = (char*)d_ws;
    size_t off = 0;
    auto alloc = [&](size_t bytes) { size_t o = off; off = (off + bytes + 255) & ~(size_t)255; return (void*)(ws + o); };
    int*   bucket_cursor = (int*)  alloc((size_t)NB * 4);
    int4*  rowmeta       = (int4*) alloc((size_t)N * 16);
    int*   csr_src       = (int*)  alloc((size_t)NB * CAPP * 4);   // fixed-stride padded CSR
    float* dis           = (float*)alloc((size_t)N * 4);
    unsigned short* w1t  = (unsigned short*)alloc((size_t)F_IN * HID * 2);
    size_t h1b_bytes  = (size_t)(N + 1) * HID * 2;                 // 12.80 MB
    size_t part_bytes = (size_t)NB * CAP * 4;                      // 12.81 MB
    unsigned short* h1b  = (unsigned short*)alloc(h1b_bytes > part_bytes ? h1b_bytes : part_bytes);
    unsigned short* h2b  = (unsigned short*)alloc((size_t)(N + 1) * NCLS * 2); // +1 sentinel row
    // part[] aliases h1b: dead before gemm1 writes h1b (alloc = max of both sizes)
    unsigned int* part   = (unsigned int*)h1b;

    init_kernel    <<<1, 256, 0, stream>>>(bucket_cursor, W1, w1t, h2b, N, NB);
    scatter_kernel <<<nchunks, 256, 0, stream>>>(src, dst, bucket_cursor, part, E, NB);
    csr_build      <<<NB, 512, 0, stream>>>(part, bucket_cursor, csr_src, rowmeta, dis, N);
    gemm1_kernel   <<<(N + 64) / 64, 256, 0, stream>>>(x, w1t, dis, h1b, N);  // +1 covers row N
    agg1_fused     <<<(N + 15) / 16, 256, 0, stream>>>(rowmeta, csr_src, h1b, b1, W2, h2b, N);
    agg2_fused     <<<(N + 31) / 32, 256, 0, stream>>>(rowmeta, csr_src, h2b, b2, out, N);
}